// Round 1
// baseline (4082.785 us; speedup 1.0000x reference)
//
#include <hip/hip_runtime.h>

constexpr int D = 256;
constexpr int S = 4096;
constexpr int BATCH = 4;
constexpr int NROWS = BATCH * S;      // 16384
constexpr float SCALE = 0.0625f;      // 1/sqrt(256)

// ---------------------------------------------------------------------------
// GEMM body: out[64 x 256] = X[64 x 256] @ W[256 x 256] + bias
// X rows taken from `in` (row stride in_stride, column offset col_off).
// 256 threads; thread owns 8 rows x 8 cols. Safe for in == out (load tile ->
// barrier -> compute from LDS -> store same rows).
// ---------------------------------------------------------------------------
__device__ __forceinline__ void gemm256_body(
    const float* in, int in_stride, int col_off,
    const float* __restrict__ W, const float* __restrict__ bias,
    float* out, int rb)
{
  __shared__ float xs[64][256];   // 64 KB
  const int tid = threadIdx.x;
#pragma unroll
  for (int it = 0; it < 16; ++it) {
    int f4 = it * 256 + tid;
    int row = f4 >> 6;            // 64 float4 per row
    int c4 = (f4 & 63) << 2;
    *(float4*)&xs[row][c4] =
        *(const float4*)(in + (size_t)(rb + row) * in_stride + col_off + c4);
  }
  __syncthreads();

  const int c0 = (tid & 31) * 8;  // 32 col-groups of 8
  const int r0 = (tid >> 5) * 8;  // 8 row-groups of 8
  float acc[8][8];
#pragma unroll
  for (int rr = 0; rr < 8; ++rr)
#pragma unroll
    for (int cc = 0; cc < 8; ++cc) acc[rr][cc] = 0.0f;

  for (int i4 = 0; i4 < 64; ++i4) {
    float4 x4[8];
#pragma unroll
    for (int rr = 0; rr < 8; ++rr)
      x4[rr] = *(const float4*)&xs[r0 + rr][i4 * 4];
#pragma unroll
    for (int di = 0; di < 4; ++di) {
      const float* wrow = W + (size_t)(i4 * 4 + di) * 256 + c0;
      float4 w0 = *(const float4*)(wrow);
      float4 w1 = *(const float4*)(wrow + 4);
#pragma unroll
      for (int rr = 0; rr < 8; ++rr) {
        float xv = (di == 0) ? x4[rr].x
                 : (di == 1) ? x4[rr].y
                 : (di == 2) ? x4[rr].z : x4[rr].w;
        acc[rr][0] += xv * w0.x;
        acc[rr][1] += xv * w0.y;
        acc[rr][2] += xv * w0.z;
        acc[rr][3] += xv * w0.w;
        acc[rr][4] += xv * w1.x;
        acc[rr][5] += xv * w1.y;
        acc[rr][6] += xv * w1.z;
        acc[rr][7] += xv * w1.w;
      }
    }
  }

  float4 b0 = *(const float4*)(bias + c0);
  float4 b1 = *(const float4*)(bias + c0 + 4);
#pragma unroll
  for (int rr = 0; rr < 8; ++rr) {
    float4 v0, v1;
    v0.x = acc[rr][0] + b0.x;
    v0.y = acc[rr][1] + b0.y;
    v0.z = acc[rr][2] + b0.z;
    v0.w = acc[rr][3] + b0.w;
    v1.x = acc[rr][4] + b1.x;
    v1.y = acc[rr][5] + b1.y;
    v1.z = acc[rr][6] + b1.z;
    v1.w = acc[rr][7] + b1.w;
    float* op = out + (size_t)(rb + r0 + rr) * 256 + c0;
    *(float4*)op = v0;
    *(float4*)(op + 4) = v1;
  }
}

__global__ __launch_bounds__(256)
void qkv_kernel(const float* __restrict__ in,
                const float* __restrict__ wq, const float* __restrict__ bq,
                const float* __restrict__ wk, const float* __restrict__ bk,
                const float* __restrict__ wv, const float* __restrict__ bv,
                float* Qo, float* Ko, float* Vo)
{
  const int m = blockIdx.y;
  const float* W    = (m == 0) ? wq : (m == 1) ? wk : wv;
  const float* bias = (m == 0) ? bq : (m == 1) ? bk : bv;
  float* out        = (m == 0) ? Qo : (m == 1) ? Ko : Vo;
  gemm256_body(in, 3 * D, m * D, W, bias, out, blockIdx.x * 64);
}

__global__ __launch_bounds__(256)
void oproj_kernel(const float* __restrict__ wo, const float* __restrict__ bo,
                  float* out)
{
  // in-place: x tile is fully loaded to LDS before rows are overwritten
  gemm256_body(out, D, 0, wo, bo, out, blockIdx.x * 64);
}

// ---------------------------------------------------------------------------
// Flash attention, fp32 vector ALU. One block = 32 query rows of one batch.
// 256 threads = (r = tid&31 query row, g = tid>>5 group). K/V are read
// directly from global (each 16B line consumed by exactly one wave-instr as a
// 32-lane broadcast -> LDS staging would add traffic with zero reuse).
// LDS: Q tile (scaled, reuse x4), 32x32 score tile, softmax state. ~38 KB.
// ---------------------------------------------------------------------------
__global__ __launch_bounds__(256)
void attn_kernel(const float* __restrict__ Qg, const float* __restrict__ Kg,
                 const float* __restrict__ Vg, float* __restrict__ X)
{
  __shared__ float Qs[32][260];   // pad: stride 260 (16B-aligned rows, 4-way max alias)
  __shared__ float Ss[32][33];    // stride 33: conflict-free b32
  __shared__ float mrow[32], lrow[32], arow[32];

  const int tid = threadIdx.x;
  const int qt = blockIdx.x;      // 0..127
  const int b  = blockIdx.y;      // 0..3
  const size_t base = (size_t)b * S * D;
  const int q0 = qt * 32;

  // load Q tile, pre-scaled by 1/sqrt(dk)
#pragma unroll
  for (int it = 0; it < 8; ++it) {
    int f4 = it * 256 + tid;
    int row = f4 >> 6;
    int c4 = (f4 & 63) << 2;
    float4 v = *(const float4*)(Qg + base + (size_t)(q0 + row) * D + c4);
    v.x *= SCALE; v.y *= SCALE; v.z *= SCALE; v.w *= SCALE;
    *(float4*)&Qs[row][c4] = v;
  }
  if (tid < 32) { mrow[tid] = -3.0e38f; lrow[tid] = 0.0f; }
  __syncthreads();

  const int r  = tid & 31;
  const int g  = tid >> 5;        // 0..7
  const int d0 = g * 32;          // this thread's 32-dim chunk of O
  const int j0 = g * 4;           // this thread's 4 score columns

  float o[32];
#pragma unroll
  for (int i = 0; i < 32; ++i) o[i] = 0.0f;

  for (int kt = 0; kt < 128; ++kt) {
    const float* kt_base = Kg + base + (size_t)kt * 32 * D;
    const float* vt_base = Vg + base + (size_t)kt * 32 * D;

    // ---- S tile: S[r][j0..j0+3] = Qs[r] . K[j] (K from global, broadcast)
    {
      const float* kp0 = kt_base + (size_t)(j0 + 0) * D;
      const float* kp1 = kt_base + (size_t)(j0 + 1) * D;
      const float* kp2 = kt_base + (size_t)(j0 + 2) * D;
      const float* kp3 = kt_base + (size_t)(j0 + 3) * D;
      float s0 = 0.0f, s1 = 0.0f, s2 = 0.0f, s3 = 0.0f;
#pragma unroll 4
      for (int i4 = 0; i4 < 64; ++i4) {
        float4 q4 = *(const float4*)&Qs[r][i4 * 4];
        float4 k0 = *(const float4*)(kp0 + i4 * 4);
        float4 k1 = *(const float4*)(kp1 + i4 * 4);
        float4 k2 = *(const float4*)(kp2 + i4 * 4);
        float4 k3 = *(const float4*)(kp3 + i4 * 4);
        s0 += q4.x * k0.x + q4.y * k0.y + q4.z * k0.z + q4.w * k0.w;
        s1 += q4.x * k1.x + q4.y * k1.y + q4.z * k1.z + q4.w * k1.w;
        s2 += q4.x * k2.x + q4.y * k2.y + q4.z * k2.z + q4.w * k2.w;
        s3 += q4.x * k3.x + q4.y * k3.y + q4.z * k3.z + q4.w * k3.w;
      }
      Ss[r][j0 + 0] = s0;
      Ss[r][j0 + 1] = s1;
      Ss[r][j0 + 2] = s2;
      Ss[r][j0 + 3] = s3;
    }
    __syncthreads();

    // ---- online softmax over this 32-key tile (one thread per query row)
    if (tid < 32) {
      float m_old = mrow[tid];
      float mx = m_old;
#pragma unroll
      for (int j = 0; j < 32; ++j) mx = fmaxf(mx, Ss[tid][j]);
      float alpha = __expf(m_old - mx);   // first iter: exp(-3e38) == 0
      float l = lrow[tid] * alpha;
#pragma unroll
      for (int j = 0; j < 32; ++j) {
        float p = __expf(Ss[tid][j] - mx);
        Ss[tid][j] = p;
        l += p;
      }
      mrow[tid] = mx;
      lrow[tid] = l;
      arow[tid] = alpha;
    }
    __syncthreads();

    // ---- O update: o = alpha*o + P[r][:] @ V[:, d0..d0+31] (V from global)
    {
      float alpha = arow[r];
#pragma unroll
      for (int i = 0; i < 32; ++i) o[i] *= alpha;
#pragma unroll 2
      for (int j = 0; j < 32; ++j) {
        float p = Ss[r][j];
        const float* vp = vt_base + (size_t)j * D + d0;
#pragma unroll
        for (int s4 = 0; s4 < 8; ++s4) {
          float4 v4 = *(const float4*)(vp + s4 * 4);
          o[s4 * 4 + 0] += p * v4.x;
          o[s4 * 4 + 1] += p * v4.y;
          o[s4 * 4 + 2] += p * v4.z;
          o[s4 * 4 + 3] += p * v4.w;
        }
      }
    }
    __syncthreads();   // Ss/arow reused next iteration
  }

  // ---- epilogue: normalize and store x (pre-output-projection) into d_out
  const float inv_l = 1.0f / lrow[r];
  float* xp = X + base + (size_t)(q0 + r) * D + d0;
#pragma unroll
  for (int s4 = 0; s4 < 8; ++s4) {
    float4 v;
    v.x = o[s4 * 4 + 0] * inv_l;
    v.y = o[s4 * 4 + 1] * inv_l;
    v.z = o[s4 * 4 + 2] * inv_l;
    v.w = o[s4 * 4 + 3] * inv_l;
    *(float4*)(xp + s4 * 4) = v;
  }
}

// ---------------------------------------------------------------------------
extern "C" void kernel_launch(void* const* d_in, const int* in_sizes, int n_in,
                              void* d_out, int out_size, void* d_ws, size_t ws_size,
                              hipStream_t stream)
{
  const float* inp = (const float*)d_in[0];
  const float* wq  = (const float*)d_in[1];
  const float* bq  = (const float*)d_in[2];
  const float* wk  = (const float*)d_in[3];
  const float* bk  = (const float*)d_in[4];
  const float* wv  = (const float*)d_in[5];
  const float* bv  = (const float*)d_in[6];
  const float* wo  = (const float*)d_in[7];
  const float* bo  = (const float*)d_in[8];
  float* out = (float*)d_out;

  // workspace: Q, K, V, each 16384x256 fp32 (16 MiB) -> 48 MiB total
  float* Qw = (float*)d_ws;
  float* Kw = Qw + (size_t)NROWS * D;
  float* Vw = Kw + (size_t)NROWS * D;

  // 1) fused QKV projections (one launch, blockIdx.y selects matrix)
  qkv_kernel<<<dim3(NROWS / 64, 3), 256, 0, stream>>>(
      inp, wq, bq, wk, bk, wv, bv, Qw, Kw, Vw);

  // 2) flash attention -> writes pre-projection x into d_out
  attn_kernel<<<dim3(S / 32, BATCH), 256, 0, stream>>>(Qw, Kw, Vw, out);

  // 3) output projection, in-place on d_out
  oproj_kernel<<<NROWS / 64, 256, 0, stream>>>(wo, bo, out);
}

// Round 3
// 717.433 us; speedup vs baseline: 5.6908x; 5.6908x over previous
//
#include <hip/hip_runtime.h>

typedef short bf16x4 __attribute__((ext_vector_type(4)));
typedef short bf16x8 __attribute__((ext_vector_type(8)));
typedef float f32x4  __attribute__((ext_vector_type(4)));

// 16x16x16 bf16 (CDNA2+ name, valid on gfx950: v_mfma_f32_16x16x16_bf16)
#define MFMA16(a, b, c) __builtin_amdgcn_mfma_f32_16x16x16bf16_1k(a, b, c, 0, 0, 0)
// 16x16x32 bf16 (gfx950)
#define MFMA32(a, b, c) __builtin_amdgcn_mfma_f32_16x16x32_bf16(a, b, c, 0, 0, 0)

constexpr int D = 256;
constexpr int S = 4096;
constexpr int BATCH = 4;
constexpr int NROWS = BATCH * S;   // 16384
constexpr float SCALE = 0.0625f;   // 1/sqrt(256)

// ---------------- bf16 split helpers (RNE) ----------------
__device__ __forceinline__ unsigned short f2bf(float v) {
  union { float f; unsigned u; } x; x.f = v;
  unsigned r = x.u + 0x7fffu + ((x.u >> 16) & 1u);
  return (unsigned short)(r >> 16);
}
__device__ __forceinline__ float bf2f(unsigned short h) {
  union { unsigned u; float f; } x; x.u = ((unsigned)h) << 16; return x.f;
}
__device__ __forceinline__ void split2(float v, unsigned short& hi, unsigned short& lo) {
  hi = f2bf(v);
  lo = f2bf(v - bf2f(hi));
}

union U8 { unsigned short s[8]; uint4 v; };

// ---------------------------------------------------------------------------
// QKV projection: out[64x256] = X[64x256] @ W + b, then split to bf16 hi/lo.
// Q scaled by 1/16. V written transposed per batch: Vt[b][dim][seq].
// ---------------------------------------------------------------------------
__global__ __launch_bounds__(256)
void qkv_split_kernel(const float* __restrict__ in,
                      const float* __restrict__ wq, const float* __restrict__ bq,
                      const float* __restrict__ wk, const float* __restrict__ bk,
                      const float* __restrict__ wv, const float* __restrict__ bv,
                      unsigned short* __restrict__ Qh, unsigned short* __restrict__ Ql,
                      unsigned short* __restrict__ Kh, unsigned short* __restrict__ Kl,
                      unsigned short* __restrict__ Vth, unsigned short* __restrict__ Vtl)
{
  const int m = blockIdx.y;
  const float* W    = (m == 0) ? wq : (m == 1) ? wk : wv;
  const float* bias = (m == 0) ? bq : (m == 1) ? bk : bv;
  const int rb = blockIdx.x * 64;
  const int col_off = m * D;

  __shared__ float xs[64][256];
  const int tid = threadIdx.x;
#pragma unroll
  for (int it = 0; it < 16; ++it) {
    int f4 = it * 256 + tid;
    int row = f4 >> 6;
    int c4 = (f4 & 63) << 2;
    *(float4*)&xs[row][c4] =
        *(const float4*)(in + (size_t)(rb + row) * (3 * D) + col_off + c4);
  }
  __syncthreads();

  const int c0 = (tid & 31) * 8;
  const int r0 = (tid >> 5) * 8;
  float acc[8][8];
#pragma unroll
  for (int rr = 0; rr < 8; ++rr)
#pragma unroll
    for (int cc = 0; cc < 8; ++cc) acc[rr][cc] = 0.0f;

  for (int i4 = 0; i4 < 64; ++i4) {
    float4 x4[8];
#pragma unroll
    for (int rr = 0; rr < 8; ++rr)
      x4[rr] = *(const float4*)&xs[r0 + rr][i4 * 4];
#pragma unroll
    for (int di = 0; di < 4; ++di) {
      const float* wrow = W + (size_t)(i4 * 4 + di) * 256 + c0;
      float4 w0 = *(const float4*)(wrow);
      float4 w1 = *(const float4*)(wrow + 4);
#pragma unroll
      for (int rr = 0; rr < 8; ++rr) {
        float xv = (di == 0) ? x4[rr].x
                 : (di == 1) ? x4[rr].y
                 : (di == 2) ? x4[rr].z : x4[rr].w;
        acc[rr][0] += xv * w0.x;  acc[rr][1] += xv * w0.y;
        acc[rr][2] += xv * w0.z;  acc[rr][3] += xv * w0.w;
        acc[rr][4] += xv * w1.x;  acc[rr][5] += xv * w1.y;
        acc[rr][6] += xv * w1.z;  acc[rr][7] += xv * w1.w;
      }
    }
  }

  float bv8[8];
#pragma unroll
  for (int cc = 0; cc < 8; ++cc) bv8[cc] = bias[c0 + cc];

  if (m < 2) {
    unsigned short* H = (m == 0) ? Qh : Kh;
    unsigned short* L = (m == 0) ? Ql : Kl;
    const float sc = (m == 0) ? SCALE : 1.0f;
#pragma unroll
    for (int rr = 0; rr < 8; ++rr) {
      U8 uh, ul;
#pragma unroll
      for (int cc = 0; cc < 8; ++cc) {
        float v = (acc[rr][cc] + bv8[cc]) * sc;
        split2(v, uh.s[cc], ul.s[cc]);
      }
      size_t a = (size_t)(rb + r0 + rr) * 256 + c0;
      *(uint4*)&H[a] = uh.v;
      *(uint4*)&L[a] = ul.v;
    }
  } else {
    const int b  = (rb + r0) >> 12;
    const int s0 = (rb + r0) & 4095;
#pragma unroll
    for (int cc = 0; cc < 8; ++cc) {
      U8 uh, ul;
#pragma unroll
      for (int rr = 0; rr < 8; ++rr) {
        float v = acc[rr][cc] + bv8[cc];
        split2(v, uh.s[rr], ul.s[rr]);
      }
      size_t a = ((size_t)(b * 256 + c0 + cc)) * 4096 + s0;
      *(uint4*)&Vth[a] = uh.v;
      *(uint4*)&Vtl[a] = ul.v;
    }
  }
}

// ---------------------------------------------------------------------------
// Output projection, fp32 in-place on d_out (tile loaded to LDS first).
// ---------------------------------------------------------------------------
__global__ __launch_bounds__(256)
void oproj_kernel(const float* __restrict__ wo, const float* __restrict__ bo,
                  float* out)
{
  const int rb = blockIdx.x * 64;
  __shared__ float xs[64][256];
  const int tid = threadIdx.x;
#pragma unroll
  for (int it = 0; it < 16; ++it) {
    int f4 = it * 256 + tid;
    int row = f4 >> 6;
    int c4 = (f4 & 63) << 2;
    *(float4*)&xs[row][c4] = *(const float4*)(out + (size_t)(rb + row) * 256 + c4);
  }
  __syncthreads();

  const int c0 = (tid & 31) * 8;
  const int r0 = (tid >> 5) * 8;
  float acc[8][8];
#pragma unroll
  for (int rr = 0; rr < 8; ++rr)
#pragma unroll
    for (int cc = 0; cc < 8; ++cc) acc[rr][cc] = 0.0f;

  for (int i4 = 0; i4 < 64; ++i4) {
    float4 x4[8];
#pragma unroll
    for (int rr = 0; rr < 8; ++rr)
      x4[rr] = *(const float4*)&xs[r0 + rr][i4 * 4];
#pragma unroll
    for (int di = 0; di < 4; ++di) {
      const float* wrow = wo + (size_t)(i4 * 4 + di) * 256 + c0;
      float4 w0 = *(const float4*)(wrow);
      float4 w1 = *(const float4*)(wrow + 4);
#pragma unroll
      for (int rr = 0; rr < 8; ++rr) {
        float xv = (di == 0) ? x4[rr].x
                 : (di == 1) ? x4[rr].y
                 : (di == 2) ? x4[rr].z : x4[rr].w;
        acc[rr][0] += xv * w0.x;  acc[rr][1] += xv * w0.y;
        acc[rr][2] += xv * w0.z;  acc[rr][3] += xv * w0.w;
        acc[rr][4] += xv * w1.x;  acc[rr][5] += xv * w1.y;
        acc[rr][6] += xv * w1.z;  acc[rr][7] += xv * w1.w;
      }
    }
  }

  float4 b0 = *(const float4*)(bo + c0);
  float4 b1 = *(const float4*)(bo + c0 + 4);
#pragma unroll
  for (int rr = 0; rr < 8; ++rr) {
    float4 v0, v1;
    v0.x = acc[rr][0] + b0.x; v0.y = acc[rr][1] + b0.y;
    v0.z = acc[rr][2] + b0.z; v0.w = acc[rr][3] + b0.w;
    v1.x = acc[rr][4] + b1.x; v1.y = acc[rr][5] + b1.y;
    v1.z = acc[rr][6] + b1.z; v1.w = acc[rr][7] + b1.w;
    float* op = out + (size_t)(rb + r0 + rr) * 256 + c0;
    *(float4*)op = v0;
    *(float4*)(op + 4) = v1;
  }
}

// ---------------------------------------------------------------------------
// MFMA flash attention (split-bf16, 3-pass). 256 blocks x 512 thr (8 waves).
// blockIdx.x: combo = x&7 -> (batch = combo>>1, khalf = combo&1); qtile = x>>3.
// Wave w owns q rows qtile*128 + w*16. S^T = K.Q^T so that P exits softmax
// already in the mfma_16x16x16 A-layout (m=lane&15=q, k=quad*4+j=key).
// K tile and transposed-V tile staged in LDS with register prefetch.
// kz=0 partial goes to Xp (=d_out, overwritten by merge), kz=1 to Op (ws).
// ---------------------------------------------------------------------------
__global__ __launch_bounds__(512, 2)
void attn2_kernel(const unsigned short* __restrict__ Qh, const unsigned short* __restrict__ Ql,
                  const unsigned short* __restrict__ Kh, const unsigned short* __restrict__ Kl,
                  const unsigned short* __restrict__ Vth, const unsigned short* __restrict__ Vtl,
                  float* __restrict__ Xp, float* __restrict__ Op,
                  float* __restrict__ Mp, float* __restrict__ Lp)
{
  __shared__ __align__(16) unsigned short KHs[16 * 264];   // stride 264
  __shared__ __align__(16) unsigned short KLs[16 * 264];
  __shared__ __align__(16) unsigned short VHs[256 * 24];   // Vt[dim][key], stride 24
  __shared__ __align__(16) unsigned short VLs[256 * 24];

  const int tid  = threadIdx.x;
  const int lane = tid & 63;
  const int wv   = tid >> 6;        // wave 0..7
  const int l15  = lane & 15;
  const int quad = lane >> 4;

  const int bx    = blockIdx.x;     // 0..255 ; XCD = bx%8 -> combo pinned per XCD
  const int combo = bx & 7;
  const int b     = combo >> 1;
  const int kz    = combo & 1;
  const int qt    = bx >> 3;        // 0..31
  const int qrow0 = qt * 128 + wv * 16;   // within batch
  const int k0    = kz * 2048;

  // ---- resident Q B-fragments (n = lane&15 = q, k = quad*8+j)
  bf16x8 qbh[8], qbl[8];
  {
    const size_t qoff = ((size_t)b * 4096 + qrow0 + l15) * 256 + quad * 8;
#pragma unroll
    for (int ks = 0; ks < 8; ++ks) {
      qbh[ks] = *(const bf16x8*)(Qh + qoff + ks * 32);
      qbl[ks] = *(const bf16x8*)(Ql + qoff + ks * 32);
    }
  }

  // ---- staging descriptors: 2 K-chunks + 2 V-chunks of 16B per thread
  const unsigned short* kg[2];  unsigned short* kd[2];
  const unsigned short* vg[2];  unsigned short* vd[2];
#pragma unroll
  for (int i = 0; i < 2; ++i) {
    int idx  = i * 512 + tid;           // [0,1024)
    int hl   = idx >> 9;
    int krow = (idx >> 5) & 15, kch = idx & 31;
    kg[i] = (hl ? Kl : Kh) + ((size_t)b * 4096 + k0 + krow) * 256 + kch * 8;
    kd[i] = (hl ? KLs : KHs) + krow * 264 + kch * 8;
    int vdim = (idx >> 1) & 255, vch = idx & 1;
    vg[i] = (hl ? Vtl : Vth) + ((size_t)(b * 256 + vdim)) * 4096 + k0 + vch * 8;
    vd[i] = (hl ? VLs : VHs) + vdim * 24 + vch * 8;
  }

  uint4 pk[2], pv[2];
#pragma unroll
  for (int i = 0; i < 2; ++i) { pk[i] = *(const uint4*)kg[i]; pv[i] = *(const uint4*)vg[i]; }

  f32x4 o[16];
#pragma unroll
  for (int ct = 0; ct < 16; ++ct) o[ct] = (f32x4){0.f, 0.f, 0.f, 0.f};
  float m_st = -3.0e38f, l_st = 0.f;

  for (int kt = 0; kt < 128; ++kt) {
    __syncthreads();                       // all waves done reading prev tile
#pragma unroll
    for (int i = 0; i < 2; ++i) { *(uint4*)kd[i] = pk[i]; *(uint4*)vd[i] = pv[i]; }
    __syncthreads();                       // tile ready
    if (kt < 127) {
#pragma unroll
      for (int i = 0; i < 2; ++i) {
        kg[i] += 16 * 256;  vg[i] += 16;
        pk[i] = *(const uint4*)kg[i];      // prefetch overlaps compute below
        pv[i] = *(const uint4*)vg[i];
      }
    }

    // ---- S^T[key][q] = K . Q^T over d=256 (3-pass split)
    f32x4 st = (f32x4){0.f, 0.f, 0.f, 0.f};
    {
      const unsigned short* krh = KHs + l15 * 264 + quad * 8;   // A: m=lane&15=key
      const unsigned short* krl = KLs + l15 * 264 + quad * 8;
#pragma unroll
      for (int ks = 0; ks < 8; ++ks) {
        bf16x8 akh = *(const bf16x8*)(krh + ks * 32);
        bf16x8 akl = *(const bf16x8*)(krl + ks * 32);
        st = MFMA32(akh, qbh[ks], st);   // hi*hi
        st = MFMA32(akl, qbh[ks], st);   // lo*hi
        st = MFMA32(akh, qbl[ks], st);   // hi*lo
      }
    }

    // ---- online softmax: lane holds column q=lane&15, keys quad*4+r
    float t = fmaxf(fmaxf(st[0], st[1]), fmaxf(st[2], st[3]));
    t = fmaxf(t, __shfl_xor(t, 16));
    t = fmaxf(t, __shfl_xor(t, 32));
    float m_new = fmaxf(m_st, t);
    float alpha = __expf(m_st - m_new);
    float p0 = __expf(st[0] - m_new);
    float p1 = __expf(st[1] - m_new);
    float p2 = __expf(st[2] - m_new);
    float p3 = __expf(st[3] - m_new);
    float ps = (p0 + p1) + (p2 + p3);
    ps += __shfl_xor(ps, 16);
    ps += __shfl_xor(ps, 32);
    l_st = l_st * alpha + ps;
    m_st = m_new;

    // ---- P already in A-layout for 16x16x16 (m=q=lane&15, k=key=quad*4+j)
    unsigned short h0, h1, h2, h3, e0, e1, e2, e3;
    split2(p0, h0, e0); split2(p1, h1, e1); split2(p2, h2, e2); split2(p3, h3, e3);
    bf16x4 pah = (bf16x4){(short)h0, (short)h1, (short)h2, (short)h3};
    bf16x4 pal = (bf16x4){(short)e0, (short)e1, (short)e2, (short)e3};

    // ---- rescale O (O rows are q=quad*4+r; alpha lives at lane q)
    float a0 = __shfl(alpha, (quad << 2) + 0);
    float a1 = __shfl(alpha, (quad << 2) + 1);
    float a2 = __shfl(alpha, (quad << 2) + 2);
    float a3 = __shfl(alpha, (quad << 2) + 3);
#pragma unroll
    for (int ct = 0; ct < 16; ++ct) {
      o[ct][0] *= a0; o[ct][1] *= a1; o[ct][2] *= a2; o[ct][3] *= a3;
    }

    // ---- O += P @ V  (B from Vt rows: n=lane&15=dim, k=quad*4+j=key)
    {
      const unsigned short* vrh = VHs + l15 * 24 + quad * 4;
      const unsigned short* vrl = VLs + l15 * 24 + quad * 4;
#pragma unroll
      for (int ct = 0; ct < 16; ++ct) {
        bf16x4 bvh = *(const bf16x4*)(vrh + ct * 384);   // 16 dims * 24 stride
        bf16x4 bvl = *(const bf16x4*)(vrl + ct * 384);
        o[ct] = MFMA16(pah, bvh, o[ct]);
        o[ct] = MFMA16(pah, bvl, o[ct]);
        o[ct] = MFMA16(pal, bvh, o[ct]);
      }
    }
  }

  // ---- store unnormalized partial O + (m,l) for the split-K merge
  float* Od = (kz == 0) ? Xp : Op;
  const int growq = b * 4096 + qrow0;
#pragma unroll
  for (int r = 0; r < 4; ++r) {
    const size_t rowoff = (size_t)(growq + quad * 4 + r) * 256 + l15;
#pragma unroll
    for (int ct = 0; ct < 16; ++ct) Od[rowoff + ct * 16] = o[ct][r];
  }
  if (lane < 16) {
    const int mrow = kz * NROWS + growq + l15;
    Mp[mrow] = m_st;
    Lp[mrow] = l_st;
  }
}

// ---------------------------------------------------------------------------
// Split-K merge: x[row] = (w0*X + w1*Op) / (w0*l0 + w1*l1) -> d_out (in-place)
// ---------------------------------------------------------------------------
__global__ __launch_bounds__(256)
void merge_kernel(const float* __restrict__ Op, const float* __restrict__ Mp,
                  const float* __restrict__ Lp, float* __restrict__ X)
{
  int idx = blockIdx.x * 256 + threadIdx.x;    // float4 index, NROWS*64 total
  int row = idx >> 6;
  int c4  = idx & 63;
  float m0 = Mp[row], m1 = Mp[NROWS + row];
  float l0 = Lp[row], l1 = Lp[NROWS + row];
  float mm = fmaxf(m0, m1);
  float w0 = __expf(m0 - mm), w1 = __expf(m1 - mm);
  float inv = 1.0f / (w0 * l0 + w1 * l1);
  float4 x0 = ((const float4*)X)[(size_t)row * 64 + c4];
  float4 x1 = ((const float4*)Op)[(size_t)row * 64 + c4];
  float4 r;
  r.x = (w0 * x0.x + w1 * x1.x) * inv;
  r.y = (w0 * x0.y + w1 * x1.y) * inv;
  r.z = (w0 * x0.z + w1 * x1.z) * inv;
  r.w = (w0 * x0.w + w1 * x1.w) * inv;
  ((float4*)X)[(size_t)row * 64 + c4] = r;
}

// ---------------------------------------------------------------------------
extern "C" void kernel_launch(void* const* d_in, const int* in_sizes, int n_in,
                              void* d_out, int out_size, void* d_ws, size_t ws_size,
                              hipStream_t stream)
{
  const float* inp = (const float*)d_in[0];
  const float* wq  = (const float*)d_in[1];
  const float* bq  = (const float*)d_in[2];
  const float* wk  = (const float*)d_in[3];
  const float* bk  = (const float*)d_in[4];
  const float* wv  = (const float*)d_in[5];
  const float* bv  = (const float*)d_in[6];
  const float* wo  = (const float*)d_in[7];
  const float* bo  = (const float*)d_in[8];
  float* out = (float*)d_out;

  // workspace layout (~67.4 MB)
  const size_t NE = (size_t)NROWS * 256;                 // 4.19M elems
  unsigned short* Qh  = (unsigned short*)d_ws;
  unsigned short* Ql  = Qh + NE;
  unsigned short* Kh  = Ql + NE;
  unsigned short* Kl  = Kh + NE;
  unsigned short* Vth = Kl + NE;
  unsigned short* Vtl = Vth + NE;
  float* Op = (float*)(Vtl + NE);                        // NE floats (kz=1 partial)
  float* Mp = Op + NE;                                   // 2 * NROWS
  float* Lp = Mp + 2 * NROWS;                            // 2 * NROWS

  qkv_split_kernel<<<dim3(NROWS / 64, 3), 256, 0, stream>>>(
      inp, wq, bq, wk, bk, wv, bv, Qh, Ql, Kh, Kl, Vth, Vtl);

  attn2_kernel<<<256, 512, 0, stream>>>(Qh, Ql, Kh, Kl, Vth, Vtl, out, Op, Mp, Lp);

  merge_kernel<<<NROWS * 64 / 256, 256, 0, stream>>>(Op, Mp, Lp, out);

  oproj_kernel<<<NROWS / 64, 256, 0, stream>>>(wo, bo, out);
}